// Round 16
// baseline (537.108 us; speedup 1.0000x reference)
//
#include <hip/hip_runtime.h>
#include <hip/hip_cooperative_groups.h>

namespace cg = cooperative_groups;

#define N_NODES 100000
#define N_EDGES 1600000
#define IN_DIM 128
#define HID_DIM 128
#define OUT_DIM 64

// ---- bucketed CSR sort geometry ----
#define NB 391                      // buckets: id>>8, ceil(100000/256)
#define GRIDB 256                   // blocks in scat phase
#define EPB (N_EDGES / GRIDB)       // 6250 edges per scat block (exact)
#define GRIDC (2 * NB)              // 782 blocks in cooperative CSR kernel
#define EPBH ((N_EDGES + GRIDC - 1) / GRIDC)  // 2047 edges per hist block

typedef unsigned short ushort_t;
typedef unsigned int uint_t;
typedef unsigned char uchar_t;
typedef __attribute__((ext_vector_type(8))) short bf16x8;
typedef __attribute__((ext_vector_type(4))) float f32x4;

// bf16 helpers (manual, RNE pack / shift unpack)
__device__ __forceinline__ float blo(uint_t u) { return __uint_as_float(u << 16); }
__device__ __forceinline__ float bhi(uint_t u) { return __uint_as_float(u & 0xFFFF0000u); }
__device__ __forceinline__ uint_t f2b(float f) {
    uint_t u = __float_as_uint(f);
    uint_t r = u + 0x7FFFu + ((u >> 16) & 1u);
    return r >> 16;
}
__device__ __forceinline__ uint_t pk2(float a, float b) { return f2b(a) | (f2b(b) << 16); }

// ---------------- ONE cooperative kernel: zero -> hist -> scan -> scatter -> finalize ----------------

__global__ __launch_bounds__(256) void csr_coop_k(
    const int* __restrict__ src, const int* __restrict__ dst,
    int* __restrict__ bucketTot, int* __restrict__ bucketTotS,
    int* __restrict__ bucketOfs, int* __restrict__ bucketOfsS,
    int* __restrict__ fill, int* __restrict__ fillS,
    uint_t* __restrict__ ebuf, uchar_t* __restrict__ sbuf,
    int* __restrict__ ofs, int* __restrict__ esrc, int* __restrict__ dego) {
    cg::grid_group grid = cg::this_grid();
    __shared__ int sm[2400];
    int t = threadIdx.x, blk = blockIdx.x;

    // P0: zero bucket totals
    {
        int g = blk * 256 + t;
        if (g < 392) bucketTot[g] = 0;
        else if (g < 784) bucketTotS[g - 392] = 0;
    }
    grid.sync();

    // P1: per-block LDS histogram of dst>>8 and src>>8 (all 782 blocks)
    {
        int* hd = sm;
        int* hs = sm + 400;
        for (int j = t; j < NB; j += 256) { hd[j] = 0; hs[j] = 0; }
        __syncthreads();
        int e0 = blk * EPBH;
        int e1 = e0 + EPBH;
        if (e1 > N_EDGES) e1 = N_EDGES;
        for (int i = e0 + t; i < e1; i += 256) {
            atomicAdd(&hd[dst[i] >> 8], 1);
            atomicAdd(&hs[src[i] >> 8], 1);
        }
        __syncthreads();
        for (int j = t; j < NB; j += 256) {
            if (hd[j]) atomicAdd(&bucketTot[j], hd[j]);
            if (hs[j]) atomicAdd(&bucketTotS[j], hs[j]);
        }
    }
    grid.sync();

    // P2: exclusive scan of the 391 bucket totals (block 0: dst, block 1: src)
    if (blk < 2) {
        const int* tot = (blk == 0) ? bucketTot : bucketTotS;
        int* bofs = (blk == 0) ? bucketOfs : bucketOfsS;
        int* fl = (blk == 0) ? fill : fillS;
        int* a = sm;
        int* b = sm + 512;
        a[t] = (t < NB) ? tot[t] : 0;
        a[t + 256] = (t + 256 < NB) ? tot[t + 256] : 0;
        __syncthreads();
        for (int off = 1; off < 512; off <<= 1) {
            b[t] = a[t] + ((t >= off) ? a[t - off] : 0);
            b[t + 256] = a[t + 256] + ((t + 256 >= off) ? a[t + 256 - off] : 0);
            __syncthreads();
            int* tmp = a; a = b; b = tmp;
        }
        for (int idx = t; idx < NB; idx += 256) {
            int e = a[idx] - tot[idx];  // exclusive
            bofs[idx] = e;
            fl[idx] = e;
        }
        if (t == 0) bofs[NB] = N_EDGES;
    }
    grid.sync();

    // P3: dual multisplit scatter (blocks < 256 only; keeps 16-edge coalesced runs)
    if (blk < GRIDB) {
        int* lcnt = sm;
        int* base = sm + 400;
        int* lpos = sm + 800;
        int* lcntS = sm + 1200;
        int* baseS = sm + 1600;
        int* lposS = sm + 2000;
        for (int j = t; j < NB; j += 256) {
            lcnt[j] = 0; lpos[j] = 0; lcntS[j] = 0; lposS[j] = 0;
        }
        __syncthreads();
        int e0 = blk * EPB;
        for (int i = e0 + t; i < e0 + EPB; i += 256) {
            atomicAdd(&lcnt[dst[i] >> 8], 1);
            atomicAdd(&lcntS[src[i] >> 8], 1);
        }
        __syncthreads();
        for (int j = t; j < NB; j += 256) {
            int c = lcnt[j];
            base[j] = c ? atomicAdd(&fill[j], c) : 0;
            int cs = lcntS[j];
            baseS[j] = cs ? atomicAdd(&fillS[j], cs) : 0;
        }
        __syncthreads();
        for (int i = e0 + t; i < e0 + EPB; i += 256) {
            int sv = src[i], d = dst[i];
            int b = d >> 8;
            int slot = atomicAdd(&lpos[b], 1);
            ebuf[base[b] + slot] = (uint_t)sv | ((uint_t)(d & 255) << 17);
            int bs = sv >> 8;
            int slotS = atomicAdd(&lposS[bs], 1);
            sbuf[baseS[bs] + slotS] = (uchar_t)(sv & 255);
        }
    }
    grid.sync();

    // P4: blocks [0,NB): dst-bucket CSR finalize -> ofs/esrc; blocks [NB,2NB): src-degree -> dego
    {
        int* cnt = sm;
        int* s = sm + 256;
        int* fil = sm + 512;
        if (blk >= NB) {
            int b = blk - NB;
            int e0 = bucketOfsS[b], e1 = bucketOfsS[b + 1];
            cnt[t] = 0;
            __syncthreads();
            for (int i = e0 + t; i < e1; i += 256) atomicAdd(&cnt[sbuf[i]], 1);
            __syncthreads();
            int node = b * 256 + t;
            if (node < N_NODES) dego[node] = cnt[t];
        } else {
            int b = blk;
            int e0 = bucketOfs[b], e1 = bucketOfs[b + 1];
            cnt[t] = 0;
            __syncthreads();
            for (int i = e0 + t; i < e1; i += 256) atomicAdd(&cnt[ebuf[i] >> 17], 1);
            __syncthreads();
            int c = cnt[t];
            s[t] = c;
            __syncthreads();
            for (int off = 1; off < 256; off <<= 1) {
                int x = (t >= off) ? s[t - off] : 0;
                __syncthreads();
                s[t] += x;
                __syncthreads();
            }
            int excl = s[t] - c;
            int node = b * 256 + t;
            if (node < N_NODES) ofs[node] = e0 + excl;
            if (b == NB - 1 && t == 0) ofs[N_NODES] = N_EDGES;
            fil[t] = excl;
            __syncthreads();
            for (int i = e0 + t; i < e1; i += 256) {
                uint_t u = ebuf[i];
                int slot = atomicAdd(&fil[u >> 17], 1);
                esrc[e0 + slot] = (int)(u & 0x1FFFFu);
            }
        }
    }
}

// ---------------- fused prep (xs = bf16(x*rsqrt(dego))) + W fragment pack ----------------

__global__ __launch_bounds__(256) void prepw_k(const float* __restrict__ x,
                                               const int* __restrict__ dego,
                                               ushort_t* __restrict__ xs,
                                               const float* __restrict__ W1,
                                               const float* __restrict__ W2,
                                               ushort_t* __restrict__ Wf1,
                                               ushort_t* __restrict__ Wf2) {
    constexpr int NB_PREP = N_NODES * 16 / 256;  // 6250
    if ((int)blockIdx.x < NB_PREP) {
        int gid = blockIdx.x * 256 + threadIdx.x;  // one uint4 (8 elems)
        int row = gid >> 4;
        float s = rsqrtf(fmaxf((float)dego[row], 1.0f));
        const float4* xp = (const float4*)x + (size_t)gid * 2;
        float4 va = xp[0], vb = xp[1];
        ((uint4*)xs)[gid] = make_uint4(pk2(va.x * s, va.y * s), pk2(va.z * s, va.w * s),
                                       pk2(vb.x * s, vb.y * s), pk2(vb.z * s, vb.w * s));
        return;
    }
    int gid = (blockIdx.x - NB_PREP) * 256 + threadIdx.x;  // 0 .. 3071
    const float* W;
    ushort_t* Wf;
    int BN;
    if (gid < HID_DIM * 16) {
        W = W1; Wf = Wf1; BN = HID_DIM;
    } else {
        gid -= HID_DIM * 16;
        if (gid >= OUT_DIM * 16) return;
        W = W2; Wf = Wf2; BN = OUT_DIM;
    }
    int l = gid & 63;
    int kc = (gid >> 6) & 3;
    int nt = gid >> 8;
    int col = nt * 16 + (l & 15);
    int k0 = kc * 32 + (l >> 4) * 8;
    uint_t r[4];
    #pragma unroll
    for (int p = 0; p < 4; ++p)
        r[p] = pk2(W[(size_t)(k0 + 2 * p) * BN + col], W[(size_t)(k0 + 2 * p + 1) * BN + col]);
    ((uint4*)Wf)[gid] = make_uint4(r[0], r[1], r[2], r[3]);
}

#define ACC8(v)                                         \
    acc[0] += blo(v.x); acc[1] += bhi(v.x);             \
    acc[2] += blo(v.y); acc[3] += bhi(v.y);             \
    acc[4] += blo(v.z); acc[5] += bhi(v.z);             \
    acc[6] += blo(v.w); acc[7] += bhi(v.w);

// ---------------- agg over 128-dim bf16 rows: one wave/node, quarter-wave per edge, 4x unrolled ----------------

__global__ __launch_bounds__(256) void agg128_k(const ushort_t* __restrict__ xs,
                                                const int* __restrict__ esrc,
                                                const int* __restrict__ ofs,
                                                ushort_t* __restrict__ a) {
    int wid = (blockIdx.x * 256 + threadIdx.x) >> 6;
    int lane = threadIdx.x & 63;
    int q = lane >> 4, li = lane & 15;
    int beg = ofs[wid], end = ofs[wid + 1];
    float acc[8];
    #pragma unroll
    for (int i = 0; i < 8; ++i) acc[i] = 0.f;

    for (int j = beg; j < end; j += 64) {
        int m = end - j;
        if (m > 64) m = 64;
        int idx = (lane < m) ? esrc[j + lane] : 0;
        for (int t = 0; 4 * t < m; t += 4) {
            int e0 = 4 * t + q, e1 = e0 + 4, e2 = e0 + 8, e3 = e0 + 12;
            int s0 = __shfl(idx, e0 & 63);
            int s1 = __shfl(idx, e1 & 63);
            int s2 = __shfl(idx, e2 & 63);
            int s3 = __shfl(idx, e3 & 63);
            uint4 v0 = *(const uint4*)(xs + (size_t)s0 * 128 + li * 8);
            uint4 v1 = *(const uint4*)(xs + (size_t)s1 * 128 + li * 8);
            uint4 v2 = *(const uint4*)(xs + (size_t)s2 * 128 + li * 8);
            uint4 v3 = *(const uint4*)(xs + (size_t)s3 * 128 + li * 8);
            if (e0 < m) { ACC8(v0) }
            if (e1 < m) { ACC8(v1) }
            if (e2 < m) { ACC8(v2) }
            if (e3 < m) { ACC8(v3) }
        }
    }
    #pragma unroll
    for (int i = 0; i < 8; ++i) acc[i] += __shfl(acc[i], lane ^ 16);
    #pragma unroll
    for (int i = 0; i < 8; ++i) acc[i] += __shfl(acc[i], lane ^ 32);

    if (lane < 16) {
        float sc = rsqrtf(fmaxf((float)(end - beg), 1.0f));
        *(uint4*)(a + (size_t)wid * 128 + li * 8) =
            make_uint4(pk2(acc[0] * sc, acc[1] * sc), pk2(acc[2] * sc, acc[3] * sc),
                       pk2(acc[4] * sc, acc[5] * sc), pk2(acc[6] * sc, acc[7] * sc));
    }
}

// ---------------- FUSED MFMA GEMM1+GEMM2 ----------------
// Per wave: 16 rows. Phase 1: h = relu(a@W1 + b1) -> per-wave LDS tile (re-layout
// C/D -> A-frag). Phase 2 (same-wave, no barrier): ys = (h@W2)*rsqrt(dego).

__global__ __launch_bounds__(256) void mgemm12_k(const ushort_t* __restrict__ A,
                                                 const ushort_t* __restrict__ Wf1,
                                                 const ushort_t* __restrict__ Wf2,
                                                 const float* __restrict__ b1,
                                                 const int* __restrict__ dego,
                                                 ushort_t* __restrict__ ys) {
    __shared__ ushort_t Hs[4][16][136];  // 272 B row stride
    int wv = threadIdx.x >> 6;
    int l = threadIdx.x & 63;
    int r0 = (blockIdx.x * 4 + wv) * 16;
    if (r0 >= N_NODES) return;
    int q = l >> 4, li = l & 15;

    const ushort_t* ap = A + (size_t)(r0 + li) * 128 + q * 8;
    bf16x8 af[4];
    #pragma unroll
    for (int kc = 0; kc < 4; ++kc) af[kc] = *(const bf16x8*)(ap + kc * 32);

    f32x4 acc[8];
    #pragma unroll
    for (int nt = 0; nt < 8; ++nt) acc[nt] = (f32x4){0.f, 0.f, 0.f, 0.f};

    #pragma unroll
    for (int kc = 0; kc < 4; ++kc) {
        #pragma unroll
        for (int nt = 0; nt < 8; ++nt) {
            bf16x8 bfr = *(const bf16x8*)(Wf1 + ((size_t)(nt * 4 + kc) * 64 + l) * 8);
            acc[nt] = __builtin_amdgcn_mfma_f32_16x16x32_bf16(af[kc], bfr, acc[nt], 0, 0, 0);
        }
    }

    #pragma unroll
    for (int nt = 0; nt < 8; ++nt) {
        float bv = b1[nt * 16 + li];
        #pragma unroll
        for (int j = 0; j < 4; ++j) {
            float x = fmaxf(acc[nt][j] + bv, 0.0f);
            Hs[wv][q * 4 + j][nt * 16 + li] = (ushort_t)f2b(x);
        }
    }

    bf16x8 hf[4];
    #pragma unroll
    for (int kc = 0; kc < 4; ++kc)
        hf[kc] = *(const bf16x8*)&Hs[wv][li][kc * 32 + q * 8];

    f32x4 acc2[4];
    #pragma unroll
    for (int nt = 0; nt < 4; ++nt) acc2[nt] = (f32x4){0.f, 0.f, 0.f, 0.f};

    #pragma unroll
    for (int kc = 0; kc < 4; ++kc) {
        #pragma unroll
        for (int nt = 0; nt < 4; ++nt) {
            bf16x8 bfr = *(const bf16x8*)(Wf2 + ((size_t)(nt * 4 + kc) * 64 + l) * 8);
            acc2[nt] = __builtin_amdgcn_mfma_f32_16x16x32_bf16(hf[kc], bfr, acc2[nt], 0, 0, 0);
        }
    }

    int orow = r0 + q * 4;
    float os[4];
    #pragma unroll
    for (int j = 0; j < 4; ++j) os[j] = rsqrtf(fmaxf((float)dego[orow + j], 1.0f));
    #pragma unroll
    for (int nt = 0; nt < 4; ++nt) {
        #pragma unroll
        for (int j = 0; j < 4; ++j) {
            ys[(size_t)(orow + j) * 64 + nt * 16 + li] = (ushort_t)f2b(acc2[nt][j] * os[j]);
        }
    }
}

// ---------------- agg over 64-dim bf16 rows + bias -> f32 out ----------------

__global__ __launch_bounds__(256) void agg64_k(const ushort_t* __restrict__ ys,
                                               const int* __restrict__ esrc,
                                               const int* __restrict__ ofs,
                                               const float* __restrict__ b2,
                                               float* __restrict__ out) {
    int wid = (blockIdx.x * 256 + threadIdx.x) >> 6;
    int lane = threadIdx.x & 63;
    int og = lane >> 3, li = lane & 7;
    int beg = ofs[wid], end = ofs[wid + 1];
    float acc[8];
    #pragma unroll
    for (int i = 0; i < 8; ++i) acc[i] = 0.f;

    for (int j = beg; j < end; j += 64) {
        int m = end - j;
        if (m > 64) m = 64;
        int idx = (lane < m) ? esrc[j + lane] : 0;
        for (int t = 0; 8 * t < m; t += 2) {
            int e0 = 8 * t + og, e1 = e0 + 8;
            int s0 = __shfl(idx, e0 & 63);
            int s1 = __shfl(idx, e1 & 63);
            uint4 v0 = *(const uint4*)(ys + (size_t)s0 * 64 + li * 8);
            uint4 v1 = *(const uint4*)(ys + (size_t)s1 * 64 + li * 8);
            if (e0 < m) { ACC8(v0) }
            if (e1 < m) { ACC8(v1) }
        }
    }
    #pragma unroll
    for (int i = 0; i < 8; ++i) acc[i] += __shfl(acc[i], lane ^ 8);
    #pragma unroll
    for (int i = 0; i < 8; ++i) acc[i] += __shfl(acc[i], lane ^ 16);
    #pragma unroll
    for (int i = 0; i < 8; ++i) acc[i] += __shfl(acc[i], lane ^ 32);

    if (lane < 8) {
        float sc = rsqrtf(fmaxf((float)(end - beg), 1.0f));
        float4 ba = *(const float4*)(b2 + li * 8);
        float4 bb = *(const float4*)(b2 + li * 8 + 4);
        float* op = out + (size_t)wid * 64 + li * 8;
        *(float4*)op = make_float4(acc[0] * sc + ba.x, acc[1] * sc + ba.y,
                                   acc[2] * sc + ba.z, acc[3] * sc + ba.w);
        *(float4*)(op + 4) = make_float4(acc[4] * sc + bb.x, acc[5] * sc + bb.y,
                                         acc[6] * sc + bb.z, acc[7] * sc + bb.w);
    }
}

extern "C" void kernel_launch(void* const* d_in, const int* in_sizes, int n_in,
                              void* d_out, int out_size, void* d_ws, size_t ws_size,
                              hipStream_t stream) {
    const float* in_feat = (const float*)d_in[0];
    const float* W1 = (const float*)d_in[1];
    const float* b1 = (const float*)d_in[2];
    const float* W2 = (const float*)d_in[3];
    const float* b2 = (const float*)d_in[4];
    const int* src = (const int*)d_in[5];
    const int* dst = (const int*)d_in[6];
    float* out = (float*)d_out;

    // workspace layout (16B-aligned slots)
    char* w = (char*)d_ws;
    int* bucketTot = (int*)w;   w += 392 * 4;
    int* bucketTotS = (int*)w;  w += 392 * 4;
    int* fill = (int*)w;        w += 392 * 4;
    int* fillS = (int*)w;       w += 392 * 4;
    int* bucketOfs = (int*)w;   w += 400 * 4;
    int* bucketOfsS = (int*)w;  w += 400 * 4;
    int* dego = (int*)w;        w += (size_t)(N_NODES + 8) * 4;
    int* ofs = (int*)w;         w += (size_t)(N_NODES + 8) * 4;
    uint_t* ebuf = (uint_t*)w;  w += (size_t)N_EDGES * 4;
    int* esrc = (int*)w;        w += (size_t)N_EDGES * 4;
    uchar_t* sbuf = (uchar_t*)w; w += (size_t)N_EDGES;
    w += (16 - ((size_t)w & 15)) & 15;  // realign
    ushort_t* Wf1 = (ushort_t*)w; w += (size_t)HID_DIM * 16 * 16;
    ushort_t* Wf2 = (ushort_t*)w; w += (size_t)OUT_DIM * 16 * 16;
    ushort_t* bufA = (ushort_t*)w; w += (size_t)N_NODES * HID_DIM * 2;  // xs -> ys
    ushort_t* bufB = (ushort_t*)w; w += (size_t)N_NODES * HID_DIM * 2;  // a

    // CSR build: one cooperative kernel (zero -> hist -> scan -> scatter -> finalize)
    void* cargs[] = {(void*)&src, (void*)&dst, (void*)&bucketTot, (void*)&bucketTotS,
                     (void*)&bucketOfs, (void*)&bucketOfsS, (void*)&fill, (void*)&fillS,
                     (void*)&ebuf, (void*)&sbuf, (void*)&ofs, (void*)&esrc, (void*)&dego};
    hipLaunchCooperativeKernel((void*)csr_coop_k, dim3(GRIDC), dim3(256), cargs, 0, stream);

    // fused prep + W packing
    prepw_k<<<N_NODES * 16 / 256 + 12, 256, 0, stream>>>(in_feat, dego, bufA, W1, W2, Wf1, Wf2);

    // layer 1: a = bf16(invi*Agg(xs))
    agg128_k<<<N_NODES / 4, 256, 0, stream>>>(bufA, esrc, ofs, bufB);

    // fused GEMMs: h = relu(a@W1+b1); ys = (h@W2)*rsqrt(dego)
    mgemm12_k<<<(N_NODES / 16 + 3) / 4, 256, 0, stream>>>(bufB, Wf1, Wf2, b1, dego, bufA);

    // out = invi*Agg(ys) + b2
    agg64_k<<<N_NODES / 4, 256, 0, stream>>>(bufA, esrc, ofs, b2, out);
}

// Round 17
// 230.911 us; speedup vs baseline: 2.3260x; 2.3260x over previous
//
#include <hip/hip_runtime.h>

#define N_NODES 100000
#define N_EDGES 1600000
#define IN_DIM 128
#define HID_DIM 128
#define OUT_DIM 64

// ---- bucketed CSR sort geometry ----
#define NB 391                      // buckets: id>>8, ceil(100000/256)
#define GRIDB 256                   // blocks in hist/scat passes
#define EPB (N_EDGES / GRIDB)       // 6250 edges per block (exact)

typedef unsigned short ushort_t;
typedef unsigned int uint_t;
typedef unsigned char uchar_t;
typedef __attribute__((ext_vector_type(8))) short bf16x8;
typedef __attribute__((ext_vector_type(4))) float f32x4;

// bf16 helpers (manual, RNE pack / shift unpack)
__device__ __forceinline__ float blo(uint_t u) { return __uint_as_float(u << 16); }
__device__ __forceinline__ float bhi(uint_t u) { return __uint_as_float(u & 0xFFFF0000u); }
__device__ __forceinline__ uint_t f2b(float f) {
    uint_t u = __float_as_uint(f);
    uint_t r = u + 0x7FFFu + ((u >> 16) & 1u);
    return r >> 16;
}
__device__ __forceinline__ uint_t pk2(float a, float b) { return f2b(a) | (f2b(b) << 16); }

// ---------------- pass A: bucket totals for dst AND src (LDS only, no global atomics on nodes) ----------------

__global__ __launch_bounds__(256) void histdeg_k(const int* __restrict__ src,
                                                 const int* __restrict__ dst,
                                                 int* __restrict__ bucketTot,
                                                 int* __restrict__ bucketTotS) {
    __shared__ int hd[NB];
    __shared__ int hs[NB];
    int t = threadIdx.x, blk = blockIdx.x;
    for (int j = t; j < NB; j += 256) { hd[j] = 0; hs[j] = 0; }
    __syncthreads();
    int e0 = blk * EPB;
    for (int i = e0 + t; i < e0 + EPB; i += 256) {
        atomicAdd(&hd[dst[i] >> 8], 1);
        atomicAdd(&hs[src[i] >> 8], 1);
    }
    __syncthreads();
    for (int j = t; j < NB; j += 256) {
        if (hd[j]) atomicAdd(&bucketTot[j], hd[j]);
        if (hs[j]) atomicAdd(&bucketTotS[j], hs[j]);
    }
}

// ---------------- tiny dual bucket scan ----------------

__global__ __launch_bounds__(512) void bscan_k(const int* __restrict__ bucketTot,
                                               const int* __restrict__ bucketTotS,
                                               int* __restrict__ bucketOfs,
                                               int* __restrict__ fill,
                                               int* __restrict__ bucketOfsS,
                                               int* __restrict__ fillS) {
    __shared__ int s[512];
    int t = threadIdx.x;
    // dst buckets
    int v = (t < NB) ? bucketTot[t] : 0;
    s[t] = v;
    __syncthreads();
    for (int off = 1; off < 512; off <<= 1) {
        int x = (t >= off) ? s[t - off] : 0;
        __syncthreads();
        s[t] += x;
        __syncthreads();
    }
    if (t < NB) {
        int e = s[t] - v;
        bucketOfs[t] = e;
        fill[t] = e;
    }
    if (t == 0) bucketOfs[NB] = N_EDGES;
    __syncthreads();
    // src buckets
    int v2 = (t < NB) ? bucketTotS[t] : 0;
    s[t] = v2;
    __syncthreads();
    for (int off = 1; off < 512; off <<= 1) {
        int x = (t >= off) ? s[t - off] : 0;
        __syncthreads();
        s[t] += x;
        __syncthreads();
    }
    if (t < NB) {
        int e = s[t] - v2;
        bucketOfsS[t] = e;
        fillS[t] = e;
    }
    if (t == 0) bucketOfsS[NB] = N_EDGES;
}

// ---------------- pass B: dual multisplit scatter ----------------
// dst: ebuf = src | (dst&255)<<17, grouped by dst>>8.  src: sbuf = src&255 (1B), grouped by src>>8.

__global__ __launch_bounds__(256) void scat_k(const int* __restrict__ src,
                                              const int* __restrict__ dst,
                                              int* __restrict__ fill,
                                              int* __restrict__ fillS,
                                              uint_t* __restrict__ ebuf,
                                              uchar_t* __restrict__ sbuf) {
    __shared__ int lcnt[NB];
    __shared__ int base[NB];
    __shared__ int lpos[NB];
    __shared__ int lcntS[NB];
    __shared__ int baseS[NB];
    __shared__ int lposS[NB];
    int t = threadIdx.x, blk = blockIdx.x;
    for (int j = t; j < NB; j += 256) {
        lcnt[j] = 0; lpos[j] = 0; lcntS[j] = 0; lposS[j] = 0;
    }
    __syncthreads();
    int e0 = blk * EPB;
    for (int i = e0 + t; i < e0 + EPB; i += 256) {
        atomicAdd(&lcnt[dst[i] >> 8], 1);
        atomicAdd(&lcntS[src[i] >> 8], 1);
    }
    __syncthreads();
    for (int j = t; j < NB; j += 256) {
        int c = lcnt[j];
        base[j] = c ? atomicAdd(&fill[j], c) : 0;
        int cs = lcntS[j];
        baseS[j] = cs ? atomicAdd(&fillS[j], cs) : 0;
    }
    __syncthreads();
    for (int i = e0 + t; i < e0 + EPB; i += 256) {
        int sv = src[i], d = dst[i];
        int b = d >> 8;
        int slot = atomicAdd(&lpos[b], 1);
        ebuf[base[b] + slot] = (uint_t)sv | ((uint_t)(d & 255) << 17);
        int bs = sv >> 8;
        int slotS = atomicAdd(&lposS[bs], 1);
        sbuf[baseS[bs] + slotS] = (uchar_t)(sv & 255);
    }
}

// ---------------- pass C: dst-bucket CSR finalize + src-bucket degree count ----------------
// Blocks [0,NB): finalize dst bucket b -> ofs, esrc.  Blocks [NB,2NB): count src bucket -> dego.

__global__ __launch_bounds__(256) void finx_k(const uint_t* __restrict__ ebuf,
                                              const uchar_t* __restrict__ sbuf,
                                              const int* __restrict__ bucketOfs,
                                              const int* __restrict__ bucketOfsS,
                                              int* __restrict__ ofs,
                                              int* __restrict__ esrc,
                                              int* __restrict__ dego) {
    __shared__ int cnt[256];
    __shared__ int s[256];
    __shared__ int fil[256];
    int t = threadIdx.x;
    int blk = blockIdx.x;

    if (blk >= NB) {
        // src-degree count
        int b = blk - NB;
        int e0 = bucketOfsS[b], e1 = bucketOfsS[b + 1];
        cnt[t] = 0;
        __syncthreads();
        for (int i = e0 + t; i < e1; i += 256) atomicAdd(&cnt[sbuf[i]], 1);
        __syncthreads();
        int node = b * 256 + t;
        if (node < N_NODES) dego[node] = cnt[t];
        return;
    }

    int b = blk;
    int e0 = bucketOfs[b], e1 = bucketOfs[b + 1];
    cnt[t] = 0;
    __syncthreads();
    for (int i = e0 + t; i < e1; i += 256) atomicAdd(&cnt[ebuf[i] >> 17], 1);
    __syncthreads();
    int c = cnt[t];
    s[t] = c;
    __syncthreads();
    for (int off = 1; off < 256; off <<= 1) {
        int x = (t >= off) ? s[t - off] : 0;
        __syncthreads();
        s[t] += x;
        __syncthreads();
    }
    int excl = s[t] - c;
    int node = b * 256 + t;
    if (node < N_NODES) ofs[node] = e0 + excl;
    if (b == NB - 1 && t == 0) ofs[N_NODES] = N_EDGES;
    fil[t] = excl;
    __syncthreads();
    for (int i = e0 + t; i < e1; i += 256) {
        uint_t u = ebuf[i];
        int slot = atomicAdd(&fil[u >> 17], 1);
        esrc[e0 + slot] = (int)(u & 0x1FFFFu);
    }
}

// ---------------- fused prep (xs = bf16(x*rsqrt(dego))) + W fragment pack ----------------

__global__ __launch_bounds__(256) void prepw_k(const float* __restrict__ x,
                                               const int* __restrict__ dego,
                                               ushort_t* __restrict__ xs,
                                               const float* __restrict__ W1,
                                               const float* __restrict__ W2,
                                               ushort_t* __restrict__ Wf1,
                                               ushort_t* __restrict__ Wf2) {
    constexpr int NB_PREP = N_NODES * 16 / 256;  // 6250
    if ((int)blockIdx.x < NB_PREP) {
        int gid = blockIdx.x * 256 + threadIdx.x;  // one uint4 (8 elems)
        int row = gid >> 4;
        float s = rsqrtf(fmaxf((float)dego[row], 1.0f));
        const float4* xp = (const float4*)x + (size_t)gid * 2;
        float4 va = xp[0], vb = xp[1];
        ((uint4*)xs)[gid] = make_uint4(pk2(va.x * s, va.y * s), pk2(va.z * s, va.w * s),
                                       pk2(vb.x * s, vb.y * s), pk2(vb.z * s, vb.w * s));
        return;
    }
    int gid = (blockIdx.x - NB_PREP) * 256 + threadIdx.x;  // 0 .. 3071
    const float* W;
    ushort_t* Wf;
    int BN;
    if (gid < HID_DIM * 16) {
        W = W1; Wf = Wf1; BN = HID_DIM;
    } else {
        gid -= HID_DIM * 16;
        if (gid >= OUT_DIM * 16) return;
        W = W2; Wf = Wf2; BN = OUT_DIM;
    }
    int l = gid & 63;
    int kc = (gid >> 6) & 3;
    int nt = gid >> 8;
    int col = nt * 16 + (l & 15);
    int k0 = kc * 32 + (l >> 4) * 8;
    uint_t r[4];
    #pragma unroll
    for (int p = 0; p < 4; ++p)
        r[p] = pk2(W[(size_t)(k0 + 2 * p) * BN + col], W[(size_t)(k0 + 2 * p + 1) * BN + col]);
    ((uint4*)Wf)[gid] = make_uint4(r[0], r[1], r[2], r[3]);
}

#define ACC8(v)                                         \
    acc[0] += blo(v.x); acc[1] += bhi(v.x);             \
    acc[2] += blo(v.y); acc[3] += bhi(v.y);             \
    acc[4] += blo(v.z); acc[5] += bhi(v.z);             \
    acc[6] += blo(v.w); acc[7] += bhi(v.w);

// ---------------- agg over 128-dim bf16 rows: one wave/node, quarter-wave per edge, 4x unrolled ----------------

__global__ __launch_bounds__(256) void agg128_k(const ushort_t* __restrict__ xs,
                                                const int* __restrict__ esrc,
                                                const int* __restrict__ ofs,
                                                ushort_t* __restrict__ a) {
    int wid = (blockIdx.x * 256 + threadIdx.x) >> 6;
    int lane = threadIdx.x & 63;
    int q = lane >> 4, li = lane & 15;
    int beg = ofs[wid], end = ofs[wid + 1];
    float acc[8];
    #pragma unroll
    for (int i = 0; i < 8; ++i) acc[i] = 0.f;

    for (int j = beg; j < end; j += 64) {
        int m = end - j;
        if (m > 64) m = 64;
        int idx = (lane < m) ? esrc[j + lane] : 0;
        for (int t = 0; 4 * t < m; t += 4) {
            int e0 = 4 * t + q, e1 = e0 + 4, e2 = e0 + 8, e3 = e0 + 12;
            int s0 = __shfl(idx, e0 & 63);
            int s1 = __shfl(idx, e1 & 63);
            int s2 = __shfl(idx, e2 & 63);
            int s3 = __shfl(idx, e3 & 63);
            uint4 v0 = *(const uint4*)(xs + (size_t)s0 * 128 + li * 8);
            uint4 v1 = *(const uint4*)(xs + (size_t)s1 * 128 + li * 8);
            uint4 v2 = *(const uint4*)(xs + (size_t)s2 * 128 + li * 8);
            uint4 v3 = *(const uint4*)(xs + (size_t)s3 * 128 + li * 8);
            if (e0 < m) { ACC8(v0) }
            if (e1 < m) { ACC8(v1) }
            if (e2 < m) { ACC8(v2) }
            if (e3 < m) { ACC8(v3) }
        }
    }
    #pragma unroll
    for (int i = 0; i < 8; ++i) acc[i] += __shfl(acc[i], lane ^ 16);
    #pragma unroll
    for (int i = 0; i < 8; ++i) acc[i] += __shfl(acc[i], lane ^ 32);

    if (lane < 16) {
        float sc = rsqrtf(fmaxf((float)(end - beg), 1.0f));
        *(uint4*)(a + (size_t)wid * 128 + li * 8) =
            make_uint4(pk2(acc[0] * sc, acc[1] * sc), pk2(acc[2] * sc, acc[3] * sc),
                       pk2(acc[4] * sc, acc[5] * sc), pk2(acc[6] * sc, acc[7] * sc));
    }
}

// ---------------- FUSED MFMA GEMM1+GEMM2 ----------------
// Per wave: 16 rows. Phase 1: h = relu(a@W1 + b1) -> per-wave LDS tile (re-layout
// C/D -> A-frag). Phase 2 (same-wave, no barrier): ys = (h@W2)*rsqrt(dego).

__global__ __launch_bounds__(256) void mgemm12_k(const ushort_t* __restrict__ A,
                                                 const ushort_t* __restrict__ Wf1,
                                                 const ushort_t* __restrict__ Wf2,
                                                 const float* __restrict__ b1,
                                                 const int* __restrict__ dego,
                                                 ushort_t* __restrict__ ys) {
    __shared__ ushort_t Hs[4][16][136];  // 272 B row stride
    int wv = threadIdx.x >> 6;
    int l = threadIdx.x & 63;
    int r0 = (blockIdx.x * 4 + wv) * 16;
    if (r0 >= N_NODES) return;
    int q = l >> 4, li = l & 15;

    const ushort_t* ap = A + (size_t)(r0 + li) * 128 + q * 8;
    bf16x8 af[4];
    #pragma unroll
    for (int kc = 0; kc < 4; ++kc) af[kc] = *(const bf16x8*)(ap + kc * 32);

    f32x4 acc[8];
    #pragma unroll
    for (int nt = 0; nt < 8; ++nt) acc[nt] = (f32x4){0.f, 0.f, 0.f, 0.f};

    #pragma unroll
    for (int kc = 0; kc < 4; ++kc) {
        #pragma unroll
        for (int nt = 0; nt < 8; ++nt) {
            bf16x8 bfr = *(const bf16x8*)(Wf1 + ((size_t)(nt * 4 + kc) * 64 + l) * 8);
            acc[nt] = __builtin_amdgcn_mfma_f32_16x16x32_bf16(af[kc], bfr, acc[nt], 0, 0, 0);
        }
    }

    #pragma unroll
    for (int nt = 0; nt < 8; ++nt) {
        float bv = b1[nt * 16 + li];
        #pragma unroll
        for (int j = 0; j < 4; ++j) {
            float x = fmaxf(acc[nt][j] + bv, 0.0f);
            Hs[wv][q * 4 + j][nt * 16 + li] = (ushort_t)f2b(x);
        }
    }

    bf16x8 hf[4];
    #pragma unroll
    for (int kc = 0; kc < 4; ++kc)
        hf[kc] = *(const bf16x8*)&Hs[wv][li][kc * 32 + q * 8];

    f32x4 acc2[4];
    #pragma unroll
    for (int nt = 0; nt < 4; ++nt) acc2[nt] = (f32x4){0.f, 0.f, 0.f, 0.f};

    #pragma unroll
    for (int kc = 0; kc < 4; ++kc) {
        #pragma unroll
        for (int nt = 0; nt < 4; ++nt) {
            bf16x8 bfr = *(const bf16x8*)(Wf2 + ((size_t)(nt * 4 + kc) * 64 + l) * 8);
            acc2[nt] = __builtin_amdgcn_mfma_f32_16x16x32_bf16(hf[kc], bfr, acc2[nt], 0, 0, 0);
        }
    }

    int orow = r0 + q * 4;
    float os[4];
    #pragma unroll
    for (int j = 0; j < 4; ++j) os[j] = rsqrtf(fmaxf((float)dego[orow + j], 1.0f));
    #pragma unroll
    for (int nt = 0; nt < 4; ++nt) {
        #pragma unroll
        for (int j = 0; j < 4; ++j) {
            ys[(size_t)(orow + j) * 64 + nt * 16 + li] = (ushort_t)f2b(acc2[nt][j] * os[j]);
        }
    }
}

// ---------------- agg over 64-dim bf16 rows + bias -> f32 out ----------------

__global__ __launch_bounds__(256) void agg64_k(const ushort_t* __restrict__ ys,
                                               const int* __restrict__ esrc,
                                               const int* __restrict__ ofs,
                                               const float* __restrict__ b2,
                                               float* __restrict__ out) {
    int wid = (blockIdx.x * 256 + threadIdx.x) >> 6;
    int lane = threadIdx.x & 63;
    int og = lane >> 3, li = lane & 7;
    int beg = ofs[wid], end = ofs[wid + 1];
    float acc[8];
    #pragma unroll
    for (int i = 0; i < 8; ++i) acc[i] = 0.f;

    for (int j = beg; j < end; j += 64) {
        int m = end - j;
        if (m > 64) m = 64;
        int idx = (lane < m) ? esrc[j + lane] : 0;
        for (int t = 0; 8 * t < m; t += 2) {
            int e0 = 8 * t + og, e1 = e0 + 8;
            int s0 = __shfl(idx, e0 & 63);
            int s1 = __shfl(idx, e1 & 63);
            uint4 v0 = *(const uint4*)(ys + (size_t)s0 * 64 + li * 8);
            uint4 v1 = *(const uint4*)(ys + (size_t)s1 * 64 + li * 8);
            if (e0 < m) { ACC8(v0) }
            if (e1 < m) { ACC8(v1) }
        }
    }
    #pragma unroll
    for (int i = 0; i < 8; ++i) acc[i] += __shfl(acc[i], lane ^ 8);
    #pragma unroll
    for (int i = 0; i < 8; ++i) acc[i] += __shfl(acc[i], lane ^ 16);
    #pragma unroll
    for (int i = 0; i < 8; ++i) acc[i] += __shfl(acc[i], lane ^ 32);

    if (lane < 8) {
        float sc = rsqrtf(fmaxf((float)(end - beg), 1.0f));
        float4 ba = *(const float4*)(b2 + li * 8);
        float4 bb = *(const float4*)(b2 + li * 8 + 4);
        float* op = out + (size_t)wid * 64 + li * 8;
        *(float4*)op = make_float4(acc[0] * sc + ba.x, acc[1] * sc + ba.y,
                                   acc[2] * sc + ba.z, acc[3] * sc + ba.w);
        *(float4*)(op + 4) = make_float4(acc[4] * sc + bb.x, acc[5] * sc + bb.y,
                                         acc[6] * sc + bb.z, acc[7] * sc + bb.w);
    }
}

extern "C" void kernel_launch(void* const* d_in, const int* in_sizes, int n_in,
                              void* d_out, int out_size, void* d_ws, size_t ws_size,
                              hipStream_t stream) {
    const float* in_feat = (const float*)d_in[0];
    const float* W1 = (const float*)d_in[1];
    const float* b1 = (const float*)d_in[2];
    const float* W2 = (const float*)d_in[3];
    const float* b2 = (const float*)d_in[4];
    const int* src = (const int*)d_in[5];
    const int* dst = (const int*)d_in[6];
    float* out = (float*)d_out;

    // workspace layout (16B-aligned slots)
    char* w = (char*)d_ws;
    int* bucketTot = (int*)w;   w += 392 * 4;   // \ contiguous -> one small memset
    int* bucketTotS = (int*)w;  w += 392 * 4;   // /
    int* fill = (int*)w;        w += 392 * 4;
    int* fillS = (int*)w;       w += 392 * 4;
    int* bucketOfs = (int*)w;   w += 400 * 4;
    int* bucketOfsS = (int*)w;  w += 400 * 4;
    int* dego = (int*)w;        w += (size_t)(N_NODES + 8) * 4;
    int* ofs = (int*)w;         w += (size_t)(N_NODES + 8) * 4;
    uint_t* ebuf = (uint_t*)w;  w += (size_t)N_EDGES * 4;
    int* esrc = (int*)w;        w += (size_t)N_EDGES * 4;
    uchar_t* sbuf = (uchar_t*)w; w += (size_t)N_EDGES;
    w += (16 - ((size_t)w & 15)) & 15;  // realign
    ushort_t* Wf1 = (ushort_t*)w; w += (size_t)HID_DIM * 16 * 16;
    ushort_t* Wf2 = (ushort_t*)w; w += (size_t)OUT_DIM * 16 * 16;
    ushort_t* bufA = (ushort_t*)w; w += (size_t)N_NODES * HID_DIM * 2;  // xs -> ys
    ushort_t* bufB = (ushort_t*)w; w += (size_t)N_NODES * HID_DIM * 2;  // a

    // zero bucket totals (tiny)
    hipMemsetAsync(bucketTot, 0, 2 * 392 * 4, stream);

    // CSR build (no global node atomics anywhere)
    histdeg_k<<<GRIDB, 256, 0, stream>>>(src, dst, bucketTot, bucketTotS);
    bscan_k<<<1, 512, 0, stream>>>(bucketTot, bucketTotS, bucketOfs, fill, bucketOfsS, fillS);
    scat_k<<<GRIDB, 256, 0, stream>>>(src, dst, fill, fillS, ebuf, sbuf);
    finx_k<<<2 * NB, 256, 0, stream>>>(ebuf, sbuf, bucketOfs, bucketOfsS, ofs, esrc, dego);

    // fused prep + W packing
    prepw_k<<<N_NODES * 16 / 256 + 12, 256, 0, stream>>>(in_feat, dego, bufA, W1, W2, Wf1, Wf2);

    // layer 1: a = bf16(invi*Agg(xs))
    agg128_k<<<N_NODES / 4, 256, 0, stream>>>(bufA, esrc, ofs, bufB);

    // fused GEMMs: h = relu(a@W1+b1); ys = (h@W2)*rsqrt(dego)
    mgemm12_k<<<(N_NODES / 16 + 3) / 4, 256, 0, stream>>>(bufB, Wf1, Wf2, b1, dego, bufA);

    // out = invi*Agg(ys) + b2
    agg64_k<<<N_NODES / 4, 256, 0, stream>>>(bufA, esrc, ofs, b2, out);
}

// Round 18
// 223.668 us; speedup vs baseline: 2.4014x; 1.0324x over previous
//
#include <hip/hip_runtime.h>

#define N_NODES 100000
#define N_EDGES 1600000
#define IN_DIM 128
#define HID_DIM 128
#define OUT_DIM 64

// ---- bucketed CSR sort geometry ----
#define NB 391                      // buckets: id>>8, ceil(100000/256)
#define GRIDB 256                   // blocks in hist/scat passes
#define EPB (N_EDGES / GRIDB)       // 6250 edges per block (exact)
#define HSTRIDE 400                 // block-major hist row stride (ints)

typedef unsigned short ushort_t;
typedef unsigned int uint_t;
typedef unsigned char uchar_t;
typedef __attribute__((ext_vector_type(8))) short bf16x8;
typedef __attribute__((ext_vector_type(4))) float f32x4;

// bf16 helpers (manual, RNE pack / shift unpack)
__device__ __forceinline__ float blo(uint_t u) { return __uint_as_float(u << 16); }
__device__ __forceinline__ float bhi(uint_t u) { return __uint_as_float(u & 0xFFFF0000u); }
__device__ __forceinline__ uint_t f2b(float f) {
    uint_t u = __float_as_uint(f);
    uint_t r = u + 0x7FFFu + ((u >> 16) & 1u);
    return r >> 16;
}
__device__ __forceinline__ uint_t pk2(float a, float b) { return f2b(a) | (f2b(b) << 16); }

// ---------------- pass A: bucket totals + per-block histograms (dst AND src) ----------------

__global__ __launch_bounds__(256) void histdeg_k(const int* __restrict__ src,
                                                 const int* __restrict__ dst,
                                                 int* __restrict__ bucketTot,
                                                 int* __restrict__ bucketTotS,
                                                 int* __restrict__ hist,
                                                 int* __restrict__ histS) {
    __shared__ int hd[NB];
    __shared__ int hs[NB];
    int t = threadIdx.x, blk = blockIdx.x;
    for (int j = t; j < NB; j += 256) { hd[j] = 0; hs[j] = 0; }
    __syncthreads();
    int e0 = blk * EPB;
    for (int i = e0 + t; i < e0 + EPB; i += 256) {
        atomicAdd(&hd[dst[i] >> 8], 1);
        atomicAdd(&hs[src[i] >> 8], 1);
    }
    __syncthreads();
    for (int j = t; j < NB; j += 256) {
        int d = hd[j], s = hs[j];
        hist[blk * HSTRIDE + j] = d;
        histS[blk * HSTRIDE + j] = s;
        if (d) atomicAdd(&bucketTot[j], d);
        if (s) atomicAdd(&bucketTotS[j], s);
    }
}

// ---------------- tiny dual bucket scan ----------------

__global__ __launch_bounds__(512) void bscan_k(const int* __restrict__ bucketTot,
                                               const int* __restrict__ bucketTotS,
                                               int* __restrict__ bucketOfs,
                                               int* __restrict__ fill,
                                               int* __restrict__ bucketOfsS,
                                               int* __restrict__ fillS) {
    __shared__ int s[512];
    int t = threadIdx.x;
    // dst buckets
    int v = (t < NB) ? bucketTot[t] : 0;
    s[t] = v;
    __syncthreads();
    for (int off = 1; off < 512; off <<= 1) {
        int x = (t >= off) ? s[t - off] : 0;
        __syncthreads();
        s[t] += x;
        __syncthreads();
    }
    if (t < NB) {
        int e = s[t] - v;
        bucketOfs[t] = e;
        fill[t] = e;
    }
    if (t == 0) bucketOfs[NB] = N_EDGES;
    __syncthreads();
    // src buckets
    int v2 = (t < NB) ? bucketTotS[t] : 0;
    s[t] = v2;
    __syncthreads();
    for (int off = 1; off < 512; off <<= 1) {
        int x = (t >= off) ? s[t - off] : 0;
        __syncthreads();
        s[t] += x;
        __syncthreads();
    }
    if (t < NB) {
        int e = s[t] - v2;
        bucketOfsS[t] = e;
        fillS[t] = e;
    }
    if (t == 0) bucketOfsS[NB] = N_EDGES;
}

// ---------------- pass B: dual multisplit scatter (counts preloaded; ONE edge pass) ----------------

__global__ __launch_bounds__(256) void scat_k(const int* __restrict__ src,
                                              const int* __restrict__ dst,
                                              const int* __restrict__ hist,
                                              const int* __restrict__ histS,
                                              int* __restrict__ fill,
                                              int* __restrict__ fillS,
                                              uint_t* __restrict__ ebuf,
                                              uchar_t* __restrict__ sbuf) {
    __shared__ int base[NB];
    __shared__ int lpos[NB];
    __shared__ int baseS[NB];
    __shared__ int lposS[NB];
    int t = threadIdx.x, blk = blockIdx.x;
    for (int j = t; j < NB; j += 256) {
        int c = hist[blk * HSTRIDE + j];
        base[j] = c ? atomicAdd(&fill[j], c) : 0;
        lpos[j] = 0;
        int cs = histS[blk * HSTRIDE + j];
        baseS[j] = cs ? atomicAdd(&fillS[j], cs) : 0;
        lposS[j] = 0;
    }
    __syncthreads();
    int e0 = blk * EPB;
    for (int i = e0 + t; i < e0 + EPB; i += 256) {
        int sv = src[i], d = dst[i];
        int b = d >> 8;
        int slot = atomicAdd(&lpos[b], 1);
        ebuf[base[b] + slot] = (uint_t)sv | ((uint_t)(d & 255) << 17);
        int bs = sv >> 8;
        int slotS = atomicAdd(&lposS[bs], 1);
        sbuf[baseS[bs] + slotS] = (uchar_t)(sv & 255);
    }
}

// ---------------- pass C: dst finalize + src degree/prep + W pack (one launch) ----------------
// Blocks [0,NB): dst bucket -> ofs/esrc.  Blocks [NB,2NB): src bucket -> dego + xs prep.
// Blocks [2NB, 2NB+12): W fragment packing.

__global__ __launch_bounds__(256) void finx_k(const uint_t* __restrict__ ebuf,
                                              const uchar_t* __restrict__ sbuf,
                                              const int* __restrict__ bucketOfs,
                                              const int* __restrict__ bucketOfsS,
                                              int* __restrict__ ofs,
                                              int* __restrict__ esrc,
                                              int* __restrict__ dego,
                                              const float* __restrict__ x,
                                              ushort_t* __restrict__ xs,
                                              const float* __restrict__ W1,
                                              const float* __restrict__ W2,
                                              ushort_t* __restrict__ Wf1,
                                              ushort_t* __restrict__ Wf2) {
    __shared__ int cnt[256];
    __shared__ int s[256];
    __shared__ int fil[256];
    int t = threadIdx.x;
    int blk = blockIdx.x;

    if (blk >= 2 * NB) {
        // W fragment pack: Wf[(nt*4+kc)*64+lane] = 8 bf16
        int gid = (blk - 2 * NB) * 256 + t;  // 0 .. 3071
        const float* W;
        ushort_t* Wf;
        int BN;
        if (gid < HID_DIM * 16) {
            W = W1; Wf = Wf1; BN = HID_DIM;
        } else {
            gid -= HID_DIM * 16;
            if (gid >= OUT_DIM * 16) return;
            W = W2; Wf = Wf2; BN = OUT_DIM;
        }
        int l = gid & 63;
        int kc = (gid >> 6) & 3;
        int nt = gid >> 8;
        int col = nt * 16 + (l & 15);
        int k0 = kc * 32 + (l >> 4) * 8;
        uint_t r[4];
        #pragma unroll
        for (int p = 0; p < 4; ++p)
            r[p] = pk2(W[(size_t)(k0 + 2 * p) * BN + col], W[(size_t)(k0 + 2 * p + 1) * BN + col]);
        ((uint4*)Wf)[((blk - 2 * NB) * 256 + t < HID_DIM * 16) ? (blk - 2 * NB) * 256 + t
                                                               : (blk - 2 * NB) * 256 + t - HID_DIM * 16] =
            make_uint4(r[0], r[1], r[2], r[3]);
        return;
    }

    if (blk >= NB) {
        // src-degree count + xs prep for this bucket's 256 nodes
        int b = blk - NB;
        int e0 = bucketOfsS[b], e1 = bucketOfsS[b + 1];
        cnt[t] = 0;
        __syncthreads();
        for (int i = e0 + t; i < e1; i += 256) atomicAdd(&cnt[sbuf[i]], 1);
        __syncthreads();
        int node = b * 256 + t;
        if (node < N_NODES) dego[node] = cnt[t];
        // prep: xs[row] = bf16(x[row] * rsqrt(max(deg,1))) for rows in this bucket
        int nrows = N_NODES - b * 256;
        if (nrows > 256) nrows = 256;
        int chunks = nrows * 16;  // one chunk = 8 f32 -> 8 bf16
        for (int c = t; c < chunks; c += 256) {
            int lrow = c >> 4;
            int sub = c & 15;
            int row = b * 256 + lrow;
            float sc = rsqrtf(fmaxf((float)cnt[lrow], 1.0f));
            const float4* xp = (const float4*)(x + (size_t)row * 128 + sub * 8);
            float4 va = xp[0], vb = xp[1];
            *(uint4*)(xs + (size_t)row * 128 + sub * 8) =
                make_uint4(pk2(va.x * sc, va.y * sc), pk2(va.z * sc, va.w * sc),
                           pk2(vb.x * sc, vb.y * sc), pk2(vb.z * sc, vb.w * sc));
        }
        return;
    }

    int b = blk;
    int e0 = bucketOfs[b], e1 = bucketOfs[b + 1];
    cnt[t] = 0;
    __syncthreads();
    for (int i = e0 + t; i < e1; i += 256) atomicAdd(&cnt[ebuf[i] >> 17], 1);
    __syncthreads();
    int c = cnt[t];
    s[t] = c;
    __syncthreads();
    for (int off = 1; off < 256; off <<= 1) {
        int x2 = (t >= off) ? s[t - off] : 0;
        __syncthreads();
        s[t] += x2;
        __syncthreads();
    }
    int excl = s[t] - c;
    int node = b * 256 + t;
    if (node < N_NODES) ofs[node] = e0 + excl;
    if (b == NB - 1 && t == 0) ofs[N_NODES] = N_EDGES;
    fil[t] = excl;
    __syncthreads();
    for (int i = e0 + t; i < e1; i += 256) {
        uint_t u = ebuf[i];
        int slot = atomicAdd(&fil[u >> 17], 1);
        esrc[e0 + slot] = (int)(u & 0x1FFFFu);
    }
}

#define ACC8(v)                                         \
    acc[0] += blo(v.x); acc[1] += bhi(v.x);             \
    acc[2] += blo(v.y); acc[3] += bhi(v.y);             \
    acc[4] += blo(v.z); acc[5] += bhi(v.z);             \
    acc[6] += blo(v.w); acc[7] += bhi(v.w);

// ---------------- agg over 128-dim bf16 rows: one wave/node, quarter-wave per edge, 4x unrolled ----------------

__global__ __launch_bounds__(256) void agg128_k(const ushort_t* __restrict__ xs,
                                                const int* __restrict__ esrc,
                                                const int* __restrict__ ofs,
                                                ushort_t* __restrict__ a) {
    int wid = (blockIdx.x * 256 + threadIdx.x) >> 6;
    int lane = threadIdx.x & 63;
    int q = lane >> 4, li = lane & 15;
    int beg = ofs[wid], end = ofs[wid + 1];
    float acc[8];
    #pragma unroll
    for (int i = 0; i < 8; ++i) acc[i] = 0.f;

    for (int j = beg; j < end; j += 64) {
        int m = end - j;
        if (m > 64) m = 64;
        int idx = (lane < m) ? esrc[j + lane] : 0;
        for (int t = 0; 4 * t < m; t += 4) {
            int e0 = 4 * t + q, e1 = e0 + 4, e2 = e0 + 8, e3 = e0 + 12;
            int s0 = __shfl(idx, e0 & 63);
            int s1 = __shfl(idx, e1 & 63);
            int s2 = __shfl(idx, e2 & 63);
            int s3 = __shfl(idx, e3 & 63);
            uint4 v0 = *(const uint4*)(xs + (size_t)s0 * 128 + li * 8);
            uint4 v1 = *(const uint4*)(xs + (size_t)s1 * 128 + li * 8);
            uint4 v2 = *(const uint4*)(xs + (size_t)s2 * 128 + li * 8);
            uint4 v3 = *(const uint4*)(xs + (size_t)s3 * 128 + li * 8);
            if (e0 < m) { ACC8(v0) }
            if (e1 < m) { ACC8(v1) }
            if (e2 < m) { ACC8(v2) }
            if (e3 < m) { ACC8(v3) }
        }
    }
    #pragma unroll
    for (int i = 0; i < 8; ++i) acc[i] += __shfl(acc[i], lane ^ 16);
    #pragma unroll
    for (int i = 0; i < 8; ++i) acc[i] += __shfl(acc[i], lane ^ 32);

    if (lane < 16) {
        float sc = rsqrtf(fmaxf((float)(end - beg), 1.0f));
        *(uint4*)(a + (size_t)wid * 128 + li * 8) =
            make_uint4(pk2(acc[0] * sc, acc[1] * sc), pk2(acc[2] * sc, acc[3] * sc),
                       pk2(acc[4] * sc, acc[5] * sc), pk2(acc[6] * sc, acc[7] * sc));
    }
}

// ---------------- FUSED MFMA GEMM1+GEMM2 ----------------
// Per wave: 16 rows. Phase 1: h = relu(a@W1 + b1) -> per-wave LDS tile (re-layout
// C/D -> A-frag). Phase 2 (same-wave, no barrier): ys = (h@W2)*rsqrt(dego).

__global__ __launch_bounds__(256) void mgemm12_k(const ushort_t* __restrict__ A,
                                                 const ushort_t* __restrict__ Wf1,
                                                 const ushort_t* __restrict__ Wf2,
                                                 const float* __restrict__ b1,
                                                 const int* __restrict__ dego,
                                                 ushort_t* __restrict__ ys) {
    __shared__ ushort_t Hs[4][16][136];  // 272 B row stride
    int wv = threadIdx.x >> 6;
    int l = threadIdx.x & 63;
    int r0 = (blockIdx.x * 4 + wv) * 16;
    if (r0 >= N_NODES) return;
    int q = l >> 4, li = l & 15;

    const ushort_t* ap = A + (size_t)(r0 + li) * 128 + q * 8;
    bf16x8 af[4];
    #pragma unroll
    for (int kc = 0; kc < 4; ++kc) af[kc] = *(const bf16x8*)(ap + kc * 32);

    f32x4 acc[8];
    #pragma unroll
    for (int nt = 0; nt < 8; ++nt) acc[nt] = (f32x4){0.f, 0.f, 0.f, 0.f};

    #pragma unroll
    for (int kc = 0; kc < 4; ++kc) {
        #pragma unroll
        for (int nt = 0; nt < 8; ++nt) {
            bf16x8 bfr = *(const bf16x8*)(Wf1 + ((size_t)(nt * 4 + kc) * 64 + l) * 8);
            acc[nt] = __builtin_amdgcn_mfma_f32_16x16x32_bf16(af[kc], bfr, acc[nt], 0, 0, 0);
        }
    }

    #pragma unroll
    for (int nt = 0; nt < 8; ++nt) {
        float bv = b1[nt * 16 + li];
        #pragma unroll
        for (int j = 0; j < 4; ++j) {
            float x = fmaxf(acc[nt][j] + bv, 0.0f);
            Hs[wv][q * 4 + j][nt * 16 + li] = (ushort_t)f2b(x);
        }
    }

    bf16x8 hf[4];
    #pragma unroll
    for (int kc = 0; kc < 4; ++kc)
        hf[kc] = *(const bf16x8*)&Hs[wv][li][kc * 32 + q * 8];

    f32x4 acc2[4];
    #pragma unroll
    for (int nt = 0; nt < 4; ++nt) acc2[nt] = (f32x4){0.f, 0.f, 0.f, 0.f};

    #pragma unroll
    for (int kc = 0; kc < 4; ++kc) {
        #pragma unroll
        for (int nt = 0; nt < 4; ++nt) {
            bf16x8 bfr = *(const bf16x8*)(Wf2 + ((size_t)(nt * 4 + kc) * 64 + l) * 8);
            acc2[nt] = __builtin_amdgcn_mfma_f32_16x16x32_bf16(hf[kc], bfr, acc2[nt], 0, 0, 0);
        }
    }

    int orow = r0 + q * 4;
    float os[4];
    #pragma unroll
    for (int j = 0; j < 4; ++j) os[j] = rsqrtf(fmaxf((float)dego[orow + j], 1.0f));
    #pragma unroll
    for (int nt = 0; nt < 4; ++nt) {
        #pragma unroll
        for (int j = 0; j < 4; ++j) {
            ys[(size_t)(orow + j) * 64 + nt * 16 + li] = (ushort_t)f2b(acc2[nt][j] * os[j]);
        }
    }
}

// ---------------- agg over 64-dim bf16 rows + bias -> f32 out ----------------

__global__ __launch_bounds__(256) void agg64_k(const ushort_t* __restrict__ ys,
                                               const int* __restrict__ esrc,
                                               const int* __restrict__ ofs,
                                               const float* __restrict__ b2,
                                               float* __restrict__ out) {
    int wid = (blockIdx.x * 256 + threadIdx.x) >> 6;
    int lane = threadIdx.x & 63;
    int og = lane >> 3, li = lane & 7;
    int beg = ofs[wid], end = ofs[wid + 1];
    float acc[8];
    #pragma unroll
    for (int i = 0; i < 8; ++i) acc[i] = 0.f;

    for (int j = beg; j < end; j += 64) {
        int m = end - j;
        if (m > 64) m = 64;
        int idx = (lane < m) ? esrc[j + lane] : 0;
        for (int t = 0; 8 * t < m; t += 2) {
            int e0 = 8 * t + og, e1 = e0 + 8;
            int s0 = __shfl(idx, e0 & 63);
            int s1 = __shfl(idx, e1 & 63);
            uint4 v0 = *(const uint4*)(ys + (size_t)s0 * 64 + li * 8);
            uint4 v1 = *(const uint4*)(ys + (size_t)s1 * 64 + li * 8);
            if (e0 < m) { ACC8(v0) }
            if (e1 < m) { ACC8(v1) }
        }
    }
    #pragma unroll
    for (int i = 0; i < 8; ++i) acc[i] += __shfl(acc[i], lane ^ 8);
    #pragma unroll
    for (int i = 0; i < 8; ++i) acc[i] += __shfl(acc[i], lane ^ 16);
    #pragma unroll
    for (int i = 0; i < 8; ++i) acc[i] += __shfl(acc[i], lane ^ 32);

    if (lane < 8) {
        float sc = rsqrtf(fmaxf((float)(end - beg), 1.0f));
        float4 ba = *(const float4*)(b2 + li * 8);
        float4 bb = *(const float4*)(b2 + li * 8 + 4);
        float* op = out + (size_t)wid * 64 + li * 8;
        *(float4*)op = make_float4(acc[0] * sc + ba.x, acc[1] * sc + ba.y,
                                   acc[2] * sc + ba.z, acc[3] * sc + ba.w);
        *(float4*)(op + 4) = make_float4(acc[4] * sc + bb.x, acc[5] * sc + bb.y,
                                         acc[6] * sc + bb.z, acc[7] * sc + bb.w);
    }
}

extern "C" void kernel_launch(void* const* d_in, const int* in_sizes, int n_in,
                              void* d_out, int out_size, void* d_ws, size_t ws_size,
                              hipStream_t stream) {
    const float* in_feat = (const float*)d_in[0];
    const float* W1 = (const float*)d_in[1];
    const float* b1 = (const float*)d_in[2];
    const float* W2 = (const float*)d_in[3];
    const float* b2 = (const float*)d_in[4];
    const int* src = (const int*)d_in[5];
    const int* dst = (const int*)d_in[6];
    float* out = (float*)d_out;

    // workspace layout (16B-aligned slots)
    char* w = (char*)d_ws;
    int* bucketTot = (int*)w;   w += 392 * 4;   // \ contiguous -> one small memset
    int* bucketTotS = (int*)w;  w += 392 * 4;   // /
    int* fill = (int*)w;        w += 392 * 4;
    int* fillS = (int*)w;       w += 392 * 4;
    int* bucketOfs = (int*)w;   w += 400 * 4;
    int* bucketOfsS = (int*)w;  w += 400 * 4;
    int* hist = (int*)w;        w += (size_t)GRIDB * HSTRIDE * 4;
    int* histS = (int*)w;       w += (size_t)GRIDB * HSTRIDE * 4;
    int* dego = (int*)w;        w += (size_t)(N_NODES + 8) * 4;
    int* ofs = (int*)w;         w += (size_t)(N_NODES + 8) * 4;
    uint_t* ebuf = (uint_t*)w;  w += (size_t)N_EDGES * 4;
    int* esrc = (int*)w;        w += (size_t)N_EDGES * 4;
    uchar_t* sbuf = (uchar_t*)w; w += (size_t)N_EDGES;
    w += (16 - ((size_t)w & 15)) & 15;  // realign
    ushort_t* Wf1 = (ushort_t*)w; w += (size_t)HID_DIM * 16 * 16;
    ushort_t* Wf2 = (ushort_t*)w; w += (size_t)OUT_DIM * 16 * 16;
    ushort_t* bufA = (ushort_t*)w; w += (size_t)N_NODES * HID_DIM * 2;  // xs -> ys
    ushort_t* bufB = (ushort_t*)w; w += (size_t)N_NODES * HID_DIM * 2;  // a

    // zero bucket totals (tiny)
    hipMemsetAsync(bucketTot, 0, 2 * 392 * 4, stream);

    // CSR build (no global node atomics anywhere)
    histdeg_k<<<GRIDB, 256, 0, stream>>>(src, dst, bucketTot, bucketTotS, hist, histS);
    bscan_k<<<1, 512, 0, stream>>>(bucketTot, bucketTotS, bucketOfs, fill, bucketOfsS, fillS);
    scat_k<<<GRIDB, 256, 0, stream>>>(src, dst, hist, histS, fill, fillS, ebuf, sbuf);
    // finalize + degree + xs prep + W pack, one launch
    finx_k<<<2 * NB + 12, 256, 0, stream>>>(ebuf, sbuf, bucketOfs, bucketOfsS, ofs, esrc, dego,
                                            in_feat, bufA, W1, W2, Wf1, Wf2);

    // layer 1: a = bf16(invi*Agg(xs))
    agg128_k<<<N_NODES / 4, 256, 0, stream>>>(bufA, esrc, ofs, bufB);

    // fused GEMMs: h = relu(a@W1+b1); ys = (h@W2)*rsqrt(dego)
    mgemm12_k<<<(N_NODES / 16 + 3) / 4, 256, 0, stream>>>(bufB, Wf1, Wf2, b1, dego, bufA);

    // out = invi*Agg(ys) + b2
    agg64_k<<<N_NODES / 4, 256, 0, stream>>>(bufA, esrc, ofs, b2, out);
}